// Round 12
// baseline (958.459 us; speedup 1.0000x reference)
//
#include <hip/hip_runtime.h>
#include <hip/hip_fp16.h>
#include <cstdint>

// GraphSAGE 2-layer, N=200000, E=6400000, F 16->40->24, fp32 in/out.
// CSR gather with algebraic push-through of W2l/W2r:
//   g = h@W2l (fp16, 64B-stride rows -> 1 line per random gather)
//   r = h@W2r + b2 (fp32, streamed)
//   layer2: out = log_softmax(mean(g[src]) + r[n]) -- h never materialized.
// deg + fill are XCD-bucketed (8 node-buckets; csr slice 3.2MB < 4MB L2/XCD)
// AND use non-temporal loads for the 8x-streamed edge list so the stream
// does not evict the partially-filled dirty csr/deg lines from L2.
// (r8 evidence: bucketing alone left WRITE=362MB ~ 14x amplification --
//  the 51MB stream thrashed the 4MB L2. nt loads are the fix under test.)
// Gathers also nt-load csr_src so L2 stays reserved for feature arrays.

#define N_NODESC 200000
#define N_EDGESC 6400000
#define F_INC 16
#define F_HC 40
#define F_OUTC 24

constexpr int SCAN_BLOCK = 1024;
constexpr int NBLK = (N_NODESC + SCAN_BLOCK - 1) / SCAN_BLOCK; // 196
constexpr int NBUCKET = 8;
constexpr int BUCKET_SZ = N_NODESC / NBUCKET; // 25000

typedef int v4i __attribute__((ext_vector_type(4))); // native vector for nt loads

// ---------------- CSR build ----------------

// XCD-bucketed degree count: gridDim.x must be a multiple of 8. Bucket
// b = blockIdx.x & 7 (aligned with HW round-robin XCD dispatch; locality
// only, correctness independent of mapping). Bucket-b blocks grid-stride
// the FULL edge list (nt loads), counting targets in the bucket range.
__global__ void deg_kernel(const int* __restrict__ tgt, int* __restrict__ deg) {
    constexpr int NV = N_EDGESC / 4; // 1.6M int4s
    const v4i* t4 = (const v4i*)tgt;
    int bucket = blockIdx.x & (NBUCKET - 1);
    int slot = blockIdx.x >> 3;
    int nslots = gridDim.x >> 3;
    int lo = bucket * BUCKET_SZ;
    int hi = lo + BUCKET_SZ;
    int i = slot * blockDim.x + threadIdx.x;
    int stride = nslots * blockDim.x;
    for (; i < NV; i += stride) {
        v4i t = __builtin_nontemporal_load(t4 + i);
        if (t.x >= lo && t.x < hi) atomicAdd(&deg[t.x], 1);
        if (t.y >= lo && t.y < hi) atomicAdd(&deg[t.y], 1);
        if (t.z >= lo && t.z < hi) atomicAdd(&deg[t.z], 1);
        if (t.w >= lo && t.w < hi) atomicAdd(&deg[t.w], 1);
    }
}

__global__ void scan1_kernel(const int* __restrict__ deg, float* __restrict__ inv_deg,
                             int* __restrict__ row_ptr, int* __restrict__ bsum) {
    __shared__ int tmp[SCAN_BLOCK];
    int t = threadIdx.x;
    int idx = blockIdx.x * SCAN_BLOCK + t;
    int d = (idx < N_NODESC) ? deg[idx] : 0;
    if (idx < N_NODESC) inv_deg[idx] = (d > 0) ? 1.0f / (float)d : 0.0f;
    tmp[t] = d;
    __syncthreads();
    for (int off = 1; off < SCAN_BLOCK; off <<= 1) {
        int v = (t >= off) ? tmp[t - off] : 0;
        __syncthreads();
        tmp[t] += v;
        __syncthreads();
    }
    if (idx < N_NODESC) row_ptr[idx] = tmp[t] - d; // exclusive within block
    if (t == SCAN_BLOCK - 1) bsum[blockIdx.x] = tmp[t];
}

// parallel block-level scan of bsum (NBLK=196 <= 256)
__global__ void scan2_kernel(int* __restrict__ bsum) {
    __shared__ int tmp[256];
    int t = threadIdx.x;
    int v = (t < NBLK) ? bsum[t] : 0;
    tmp[t] = v;
    __syncthreads();
    for (int off = 1; off < 256; off <<= 1) {
        int u = (t >= off) ? tmp[t - off] : 0;
        __syncthreads();
        tmp[t] += u;
        __syncthreads();
    }
    if (t < NBLK) bsum[t] = tmp[t] - v; // exclusive
}

__global__ void scan3_kernel(int* __restrict__ row_ptr, const int* __restrict__ bsum,
                             int* __restrict__ fill_pos) {
    int idx = blockIdx.x * SCAN_BLOCK + threadIdx.x;
    if (idx < N_NODESC) {
        int v = row_ptr[idx] + bsum[blockIdx.x];
        row_ptr[idx] = v;
        fill_pos[idx] = v;
    }
    if (idx == 0) row_ptr[N_NODESC] = N_EDGESC;
}

// XCD-bucketed fill (same decomposition as deg_kernel), nt edge reads.
// Every edge committed exactly once: by the bucket containing its target.
// csr_src stores stay normal (cached) -- they're what we keep in L2.
__global__ void fill_kernel(const int* __restrict__ src, const int* __restrict__ tgt,
                            int* __restrict__ fill_pos, int* __restrict__ csr_src) {
    constexpr int NV = N_EDGESC / 4;
    const v4i* t4 = (const v4i*)tgt;
    const v4i* s4 = (const v4i*)src;
    int bucket = blockIdx.x & (NBUCKET - 1);
    int slot = blockIdx.x >> 3;
    int nslots = gridDim.x >> 3;
    int lo = bucket * BUCKET_SZ;
    int hi = lo + BUCKET_SZ;
    int i = slot * blockDim.x + threadIdx.x;
    int stride = nslots * blockDim.x;
    for (; i < NV; i += stride) {
        v4i t = __builtin_nontemporal_load(t4 + i);
        v4i s = __builtin_nontemporal_load(s4 + i);
        if (t.x >= lo && t.x < hi) { int p = atomicAdd(&fill_pos[t.x], 1); csr_src[p] = s.x; }
        if (t.y >= lo && t.y < hi) { int p = atomicAdd(&fill_pos[t.y], 1); csr_src[p] = s.y; }
        if (t.z >= lo && t.z < hi) { int p = atomicAdd(&fill_pos[t.z], 1); csr_src[p] = s.z; }
        if (t.w >= lo && t.w < hi) { int p = atomicAdd(&fill_pos[t.w], 1); csr_src[p] = s.w; }
    }
}

// ---------------- x -> fp16 cast ----------------

__global__ void cast_x_kernel(const float* __restrict__ x, __half* __restrict__ xh) {
    int i = blockIdx.x * blockDim.x + threadIdx.x; // one float4 per thread
    constexpr int TOT = N_NODESC * F_INC / 4;
    if (i >= TOT) return;
    float4 v = ((const float4*)x)[i];
    union { __half2 h[2]; uint2 u; } pk;
    pk.h[0] = __floats2half2_rn(v.x, v.y);
    pk.h[1] = __floats2half2_rn(v.z, v.w);
    ((uint2*)xh)[i] = pk.u;
}

// ---------------- K1: mean-gather x (fp16) -> agg (fp32, scaled) ----------------

__global__ __launch_bounds__(256) void gather1_kernel(
    const __half* __restrict__ xh, const int* __restrict__ row_ptr,
    const int* __restrict__ csr_src, const float* __restrict__ inv_deg,
    float* __restrict__ agg) {
    int gt = blockIdx.x * blockDim.x + threadIdx.x;
    int n = gt >> 2, l = gt & 3;
    if (n >= N_NODESC) return;

    float a[F_INC];
#pragma unroll
    for (int k = 0; k < F_INC; k++) a[k] = 0.0f;

    int e0 = row_ptr[n], e1 = row_ptr[n + 1];
    int e = e0 + l;
    // unroll-2: two independent gather streams in flight
    for (; e + 4 < e1; e += 8) {
        int s0 = __builtin_nontemporal_load(csr_src + e);
        int s1 = __builtin_nontemporal_load(csr_src + e + 4);
        const uint4* r0 = (const uint4*)(xh + (size_t)s0 * F_INC);
        const uint4* r1 = (const uint4*)(xh + (size_t)s1 * F_INC);
        uint4 u0 = r0[0], u1 = r0[1];
        uint4 w0 = r1[0], w1 = r1[1];
        const __half2* p;
        p = (const __half2*)&u0;
#pragma unroll
        for (int q = 0; q < 4; q++) { float2 f = __half22float2(p[q]); a[2*q] += f.x; a[2*q+1] += f.y; }
        p = (const __half2*)&u1;
#pragma unroll
        for (int q = 0; q < 4; q++) { float2 f = __half22float2(p[q]); a[8+2*q] += f.x; a[8+2*q+1] += f.y; }
        p = (const __half2*)&w0;
#pragma unroll
        for (int q = 0; q < 4; q++) { float2 f = __half22float2(p[q]); a[2*q] += f.x; a[2*q+1] += f.y; }
        p = (const __half2*)&w1;
#pragma unroll
        for (int q = 0; q < 4; q++) { float2 f = __half22float2(p[q]); a[8+2*q] += f.x; a[8+2*q+1] += f.y; }
    }
    if (e < e1) {
        int s0 = __builtin_nontemporal_load(csr_src + e);
        const uint4* r0 = (const uint4*)(xh + (size_t)s0 * F_INC);
        uint4 u0 = r0[0], u1 = r0[1];
        const __half2* p = (const __half2*)&u0;
#pragma unroll
        for (int q = 0; q < 4; q++) { float2 f = __half22float2(p[q]); a[2*q] += f.x; a[2*q+1] += f.y; }
        p = (const __half2*)&u1;
#pragma unroll
        for (int q = 0; q < 4; q++) { float2 f = __half22float2(p[q]); a[8+2*q] += f.x; a[8+2*q+1] += f.y; }
    }

    // butterfly reduce across the 4 lanes of this node
#pragma unroll
    for (int off = 1; off <= 2; off <<= 1) {
#pragma unroll
        for (int k = 0; k < F_INC; k++) a[k] += __shfl_xor(a[k], off);
    }

    float idg = inv_deg[n];
    float4 w;
    w.x = a[l*4+0] * idg; w.y = a[l*4+1] * idg;
    w.z = a[l*4+2] * idg; w.w = a[l*4+3] * idg;
    ((float4*)(agg + (size_t)n * F_INC))[l] = w;
}

// ------- K2: dense fused: h=relu(agg@W1l+b1+x@W1r); g=h@W2l (fp16); r=h@W2r+b2 -------

__global__ __launch_bounds__(256) void dense_kernel(
    const float* __restrict__ x, const float* __restrict__ agg,
    const float* __restrict__ W1l, const float* __restrict__ b1,
    const float* __restrict__ W1r, const float* __restrict__ W2l,
    const float* __restrict__ b2, const float* __restrict__ W2r,
    __half* __restrict__ g16, float* __restrict__ r) {
    __shared__ float sW1l[F_INC][F_HC];
    __shared__ float sW1r[F_INC][F_HC];
    __shared__ float sb1[F_HC];
    __shared__ float sW2l[F_HC][F_OUTC];
    __shared__ float sW2r[F_HC][F_OUTC];
    __shared__ float sb2[F_OUTC];
    for (int i = threadIdx.x; i < F_INC * F_HC; i += blockDim.x) {
        sW1l[i / F_HC][i % F_HC] = W1l[i];
        sW1r[i / F_HC][i % F_HC] = W1r[i];
    }
    for (int i = threadIdx.x; i < F_HC * F_OUTC; i += blockDim.x) {
        sW2l[i / F_OUTC][i % F_OUTC] = W2l[i];
        sW2r[i / F_OUTC][i % F_OUTC] = W2r[i];
    }
    if (threadIdx.x < F_HC) sb1[threadIdx.x] = b1[threadIdx.x];
    if (threadIdx.x < F_OUTC) sb2[threadIdx.x] = b2[threadIdx.x];
    __syncthreads();

    int n = blockIdx.x * blockDim.x + threadIdx.x;
    if (n >= N_NODESC) return;

    float ag[F_INC], xr[F_INC];
    const float4* ap = (const float4*)(agg + (size_t)n * F_INC);
    const float4* xp = (const float4*)(x + (size_t)n * F_INC);
#pragma unroll
    for (int q = 0; q < F_INC / 4; q++) {
        float4 v = ap[q];
        ag[4*q] = v.x; ag[4*q+1] = v.y; ag[4*q+2] = v.z; ag[4*q+3] = v.w;
        float4 u = xp[q];
        xr[4*q] = u.x; xr[4*q+1] = u.y; xr[4*q+2] = u.z; xr[4*q+3] = u.w;
    }

    float h[F_HC];
#pragma unroll
    for (int f = 0; f < F_HC; f++) h[f] = sb1[f];
#pragma unroll
    for (int k = 0; k < F_INC; k++) {
        float a = ag[k], b = xr[k];
#pragma unroll
        for (int f = 0; f < F_HC; f++) h[f] += a * sW1l[k][f] + b * sW1r[k][f];
    }
#pragma unroll
    for (int f = 0; f < F_HC; f++) h[f] = fmaxf(h[f], 0.0f);

    float g[F_OUTC], rr[F_OUTC];
#pragma unroll
    for (int f = 0; f < F_OUTC; f++) { g[f] = 0.0f; rr[f] = sb2[f]; }
#pragma unroll
    for (int k = 0; k < F_HC; k++) {
        float hv = h[k];
#pragma unroll
        for (int f = 0; f < F_OUTC; f++) {
            g[f] += hv * sW2l[k][f];
            rr[f] += hv * sW2r[k][f];
        }
    }

    // g -> fp16, 64B-stride rows (32 halves, 24 used)
    __half* gp = g16 + (size_t)n * 32;
#pragma unroll
    for (int q = 0; q < F_OUTC / 8; q++) {
        union { __half2 h2[4]; uint4 u; } pk;
#pragma unroll
        for (int j = 0; j < 4; j++)
            pk.h2[j] = __floats2half2_rn(g[8*q + 2*j], g[8*q + 2*j + 1]);
        ((uint4*)gp)[q] = pk.u;
    }
    float4* rp = (float4*)(r + (size_t)n * F_OUTC);
#pragma unroll
    for (int q = 0; q < F_OUTC / 4; q++) {
        float4 v;
        v.x = rr[4*q]; v.y = rr[4*q+1]; v.z = rr[4*q+2]; v.w = rr[4*q+3];
        rp[q] = v;
    }
}

// ------- K3: mean-gather g (fp16) + r -> log_softmax -> out -------

__global__ __launch_bounds__(256) void gather2_kernel(
    const __half* __restrict__ g16, const int* __restrict__ row_ptr,
    const int* __restrict__ csr_src, const float* __restrict__ inv_deg,
    const float* __restrict__ r, float* __restrict__ out) {
    int gt = blockIdx.x * blockDim.x + threadIdx.x;
    int n = gt >> 2, l = gt & 3;
    if (n >= N_NODESC) return;

    float a[F_OUTC];
#pragma unroll
    for (int k = 0; k < F_OUTC; k++) a[k] = 0.0f;

    int e0 = row_ptr[n], e1 = row_ptr[n + 1];
    int e = e0 + l;
    for (; e + 4 < e1; e += 8) {
        int s0 = __builtin_nontemporal_load(csr_src + e);
        int s1 = __builtin_nontemporal_load(csr_src + e + 4);
        const uint4* r0 = (const uint4*)(g16 + (size_t)s0 * 32);
        const uint4* r1 = (const uint4*)(g16 + (size_t)s1 * 32);
        uint4 u0 = r0[0], u1 = r0[1], u2 = r0[2];
        uint4 w0 = r1[0], w1 = r1[1], w2 = r1[2];
        const __half2* p;
        p = (const __half2*)&u0;
#pragma unroll
        for (int q = 0; q < 4; q++) { float2 f = __half22float2(p[q]); a[2*q] += f.x; a[2*q+1] += f.y; }
        p = (const __half2*)&u1;
#pragma unroll
        for (int q = 0; q < 4; q++) { float2 f = __half22float2(p[q]); a[8+2*q] += f.x; a[8+2*q+1] += f.y; }
        p = (const __half2*)&u2;
#pragma unroll
        for (int q = 0; q < 4; q++) { float2 f = __half22float2(p[q]); a[16+2*q] += f.x; a[16+2*q+1] += f.y; }
        p = (const __half2*)&w0;
#pragma unroll
        for (int q = 0; q < 4; q++) { float2 f = __half22float2(p[q]); a[2*q] += f.x; a[2*q+1] += f.y; }
        p = (const __half2*)&w1;
#pragma unroll
        for (int q = 0; q < 4; q++) { float2 f = __half22float2(p[q]); a[8+2*q] += f.x; a[8+2*q+1] += f.y; }
        p = (const __half2*)&w2;
#pragma unroll
        for (int q = 0; q < 4; q++) { float2 f = __half22float2(p[q]); a[16+2*q] += f.x; a[16+2*q+1] += f.y; }
    }
    if (e < e1) {
        int s0 = __builtin_nontemporal_load(csr_src + e);
        const uint4* r0 = (const uint4*)(g16 + (size_t)s0 * 32);
        uint4 u0 = r0[0], u1 = r0[1], u2 = r0[2];
        const __half2* p = (const __half2*)&u0;
#pragma unroll
        for (int q = 0; q < 4; q++) { float2 f = __half22float2(p[q]); a[2*q] += f.x; a[2*q+1] += f.y; }
        p = (const __half2*)&u1;
#pragma unroll
        for (int q = 0; q < 4; q++) { float2 f = __half22float2(p[q]); a[8+2*q] += f.x; a[8+2*q+1] += f.y; }
        p = (const __half2*)&u2;
#pragma unroll
        for (int q = 0; q < 4; q++) { float2 f = __half22float2(p[q]); a[16+2*q] += f.x; a[16+2*q+1] += f.y; }
    }

#pragma unroll
    for (int off = 1; off <= 2; off <<= 1) {
#pragma unroll
        for (int k = 0; k < F_OUTC; k++) a[k] += __shfl_xor(a[k], off);
    }

    float idg = inv_deg[n];
    const float* rb = r + (size_t)n * F_OUTC + l * 6;
    float o[6];
#pragma unroll
    for (int j = 0; j < 6; j++) o[j] = a[l * 6 + j] * idg + rb[j];

    float m = o[0];
#pragma unroll
    for (int j = 1; j < 6; j++) m = fmaxf(m, o[j]);
    m = fmaxf(m, __shfl_xor(m, 1));
    m = fmaxf(m, __shfl_xor(m, 2));
    float s = 0.0f;
#pragma unroll
    for (int j = 0; j < 6; j++) s += __expf(o[j] - m);
    s += __shfl_xor(s, 1);
    s += __shfl_xor(s, 2);
    float lse = m + __logf(s);

    float* ob = out + (size_t)n * F_OUTC + l * 6;
#pragma unroll
    for (int j = 0; j < 6; j++) ob[j] = o[j] - lse;
}

// ---------------- launch ----------------

extern "C" void kernel_launch(void* const* d_in, const int* in_sizes, int n_in,
                              void* d_out, int out_size, void* d_ws, size_t ws_size,
                              hipStream_t stream) {
    const float* x   = (const float*)d_in[0];
    const int* eidx  = (const int*)d_in[1];
    const float* W1l = (const float*)d_in[2];
    const float* b1  = (const float*)d_in[3];
    const float* W1r = (const float*)d_in[4];
    const float* W2l = (const float*)d_in[5];
    const float* b2  = (const float*)d_in[6];
    const float* W2r = (const float*)d_in[7];
    float* out = (float*)d_out;

    const int* src = eidx;
    const int* tgt = eidx + N_EDGESC;

    char* ws = (char*)d_ws;
    size_t off = 0;
    auto alloc = [&](size_t bytes) {
        size_t o = off;
        off = (off + bytes + 255) & ~(size_t)255;
        return o;
    };
    int*    deg      = (int*)(ws + alloc((size_t)N_NODESC * 4));
    int*    fill_pos = (int*)(ws + alloc((size_t)N_NODESC * 4));
    float*  inv_deg  = (float*)(ws + alloc((size_t)N_NODESC * 4));
    int*    row_ptr  = (int*)(ws + alloc((size_t)(N_NODESC + 1) * 4));
    int*    bsum     = (int*)(ws + alloc((size_t)NBLK * 4));
    int*    csr_src  = (int*)(ws + alloc((size_t)N_EDGESC * 4));
    __half* xh       = (__half*)(ws + alloc((size_t)N_NODESC * F_INC * 2));
    float*  agg      = (float*)(ws + alloc((size_t)N_NODESC * F_INC * 4));
    __half* g16      = (__half*)(ws + alloc((size_t)N_NODESC * 32 * 2));
    float*  r        = (float*)(ws + alloc((size_t)N_NODESC * F_OUTC * 4));
    (void)ws_size;

    hipMemsetAsync(deg, 0, (size_t)N_NODESC * 4, stream);

    const int TB = 256;
    const int edgeBlocks = 2560; // multiple of 8 (deg/fill bucketing requires it)
    deg_kernel<<<edgeBlocks, TB, 0, stream>>>(tgt, deg);
    cast_x_kernel<<<(N_NODESC * F_INC / 4 + TB - 1) / TB, TB, 0, stream>>>(x, xh);
    scan1_kernel<<<NBLK, SCAN_BLOCK, 0, stream>>>(deg, inv_deg, row_ptr, bsum);
    scan2_kernel<<<1, 256, 0, stream>>>(bsum);
    scan3_kernel<<<NBLK, SCAN_BLOCK, 0, stream>>>(row_ptr, bsum, fill_pos);
    fill_kernel<<<edgeBlocks, TB, 0, stream>>>(src, tgt, fill_pos, csr_src);

    const int lane4Blocks = ((N_NODESC * 4) + TB - 1) / TB; // 3125
    gather1_kernel<<<lane4Blocks, TB, 0, stream>>>(xh, row_ptr, csr_src, inv_deg, agg);
    dense_kernel<<<(N_NODESC + TB - 1) / TB, TB, 0, stream>>>(
        x, agg, W1l, b1, W1r, W2l, b2, W2r, g16, r);
    gather2_kernel<<<lane4Blocks, TB, 0, stream>>>(g16, row_ptr, csr_src, inv_deg, r, out);
}

// Round 13
// 957.080 us; speedup vs baseline: 1.0014x; 1.0014x over previous
//
#include <hip/hip_runtime.h>
#include <hip/hip_fp16.h>
#include <cstdint>

// GraphSAGE 2-layer, N=200000, E=6400000, F 16->40->24, fp32 in/out.
// CSR gather with algebraic push-through of W2l/W2r (g=h@W2l fp16 64B rows,
// r=h@W2r+b2; layer2 = log_softmax(mean(g[src]) + r) -- h never materialized).
// CSR fill is APPEND-ONLY TWO-PASS (r12 falsified cache-hint fixes for the
// positional scatter: WRITE stayed 362->401MB):
//   bin:   bucket=tgt>>4 (12500 buckets, base=row_ptr[b<<4]); append packed
//          (src<<4)|(tgt&15) at atomic cursor -> only live write lines are
//          12500 bucket tails (800KB) -> pair_buf written back once (25.6MB).
//   unbin: block per 64-node group; coalesced read of its pair slice; node
//          recovered via 4-way range search + v&15; rank via LDS atomics;
//          scatter confined to the group's ~8KB csr window (cache-resident).
// pair_buf overlays agg+g16 (dead until gather1). No nt loads (r12: regression).

#define N_NODESC 200000
#define N_EDGESC 6400000
#define F_INC 16
#define F_HC 40
#define F_OUTC 24

constexpr int SCAN_BLOCK = 1024;
constexpr int NBLK = (N_NODESC + SCAN_BLOCK - 1) / SCAN_BLOCK; // 196
constexpr int NBUCKET = 8;
constexpr int BUCKET_SZ = N_NODESC / NBUCKET; // 25000 (deg bucketing, as r8)
constexpr int NBIN = N_NODESC / 16;           // 12500 fill bins (16 nodes each)
constexpr int NGRP = N_NODESC / 64;           // 3125 unbin groups

// ---------------- CSR build ----------------

// deg: kept byte-identical to round-8 (XCD-bucketed, plain loads).
__global__ void deg_kernel(const int* __restrict__ tgt, int* __restrict__ deg) {
    constexpr int NV = N_EDGESC / 4;
    const int4* t4 = (const int4*)tgt;
    int bucket = blockIdx.x & (NBUCKET - 1);
    int slot = blockIdx.x >> 3;
    int nslots = gridDim.x >> 3;
    int lo = bucket * BUCKET_SZ;
    int hi = lo + BUCKET_SZ;
    int i = slot * blockDim.x + threadIdx.x;
    int stride = nslots * blockDim.x;
    for (; i < NV; i += stride) {
        int4 t = t4[i];
        if (t.x >= lo && t.x < hi) atomicAdd(&deg[t.x], 1);
        if (t.y >= lo && t.y < hi) atomicAdd(&deg[t.y], 1);
        if (t.z >= lo && t.z < hi) atomicAdd(&deg[t.z], 1);
        if (t.w >= lo && t.w < hi) atomicAdd(&deg[t.w], 1);
    }
}

__global__ void scan1_kernel(const int* __restrict__ deg, float* __restrict__ inv_deg,
                             int* __restrict__ row_ptr, int* __restrict__ bsum) {
    __shared__ int tmp[SCAN_BLOCK];
    int t = threadIdx.x;
    int idx = blockIdx.x * SCAN_BLOCK + t;
    int d = (idx < N_NODESC) ? deg[idx] : 0;
    if (idx < N_NODESC) inv_deg[idx] = (d > 0) ? 1.0f / (float)d : 0.0f;
    tmp[t] = d;
    __syncthreads();
    for (int off = 1; off < SCAN_BLOCK; off <<= 1) {
        int v = (t >= off) ? tmp[t - off] : 0;
        __syncthreads();
        tmp[t] += v;
        __syncthreads();
    }
    if (idx < N_NODESC) row_ptr[idx] = tmp[t] - d; // exclusive within block
    if (t == SCAN_BLOCK - 1) bsum[blockIdx.x] = tmp[t];
}

__global__ void scan2_kernel(int* __restrict__ bsum) {
    __shared__ int tmp[256];
    int t = threadIdx.x;
    int v = (t < NBLK) ? bsum[t] : 0;
    tmp[t] = v;
    __syncthreads();
    for (int off = 1; off < 256; off <<= 1) {
        int u = (t >= off) ? tmp[t - off] : 0;
        __syncthreads();
        tmp[t] += u;
        __syncthreads();
    }
    if (t < NBLK) bsum[t] = tmp[t] - v; // exclusive
}

__global__ void scan3_kernel(int* __restrict__ row_ptr, const int* __restrict__ bsum) {
    int idx = blockIdx.x * SCAN_BLOCK + threadIdx.x;
    if (idx < N_NODESC) row_ptr[idx] += bsum[blockIdx.x];
    if (idx == 0) row_ptr[N_NODESC] = N_EDGESC;
}

// Phase A: append-only binning. bucket = tgt>>4; base = row_ptr[bucket<<4]
// (CSR node order makes bucket regions contiguous). Packed entry:
// (src<<4)|(tgt&15) -- src<2^18 so 22 bits. Dense appends -> write-once lines.
__global__ void bin_kernel(const int* __restrict__ src, const int* __restrict__ tgt,
                           const int* __restrict__ row_ptr, int* __restrict__ bin_fill,
                           int* __restrict__ pair_buf) {
    constexpr int NV = N_EDGESC / 4;
    const int4* t4 = (const int4*)tgt;
    const int4* s4 = (const int4*)src;
    int i = blockIdx.x * blockDim.x + threadIdx.x;
    int stride = gridDim.x * blockDim.x;
    for (; i < NV; i += stride) {
        int4 t = t4[i];
        int4 s = s4[i];
        { int b = t.x >> 4; int p = atomicAdd(&bin_fill[b], 1);
          pair_buf[row_ptr[b << 4] + p] = (s.x << 4) | (t.x & 15); }
        { int b = t.y >> 4; int p = atomicAdd(&bin_fill[b], 1);
          pair_buf[row_ptr[b << 4] + p] = (s.y << 4) | (t.y & 15); }
        { int b = t.z >> 4; int p = atomicAdd(&bin_fill[b], 1);
          pair_buf[row_ptr[b << 4] + p] = (s.z << 4) | (t.z & 15); }
        { int b = t.w >> 4; int p = atomicAdd(&bin_fill[b], 1);
          pair_buf[row_ptr[b << 4] + p] = (s.w << 4) | (t.w & 15); }
    }
}

// Phase B: block per 64-node group (4 bins). Coalesced read of the group's
// contiguous pair slice; recover bin via 3-boundary search; rank via LDS
// atomics; final scatter lands in the group's contiguous csr window.
__global__ __launch_bounds__(256) void unbin_kernel(
    const int* __restrict__ row_ptr, const int* __restrict__ pair_buf,
    int* __restrict__ csr_src) {
    __shared__ int lbase[65];
    __shared__ int lfill[64];
    int tid = threadIdx.x;
    int g = blockIdx.x; // nodes [g*64, (g+1)*64)
    if (tid < 65) lbase[tid] = row_ptr[g * 64 + tid];
    if (tid < 64) lfill[tid] = 0;
    __syncthreads();
    int e0 = lbase[0], e1 = lbase[64];
    for (int e = e0 + tid; e < e1; e += 256) {
        int v = pair_buf[e];
        int j = (e >= lbase[32]) ? ((e >= lbase[48]) ? 48 : 32)
                                 : ((e >= lbase[16]) ? 16 : 0);
        int nl = j + (v & 15);
        int rank = atomicAdd(&lfill[nl], 1);
        csr_src[lbase[nl] + rank] = v >> 4;
    }
}

// ---------------- x -> fp16 cast ----------------

__global__ void cast_x_kernel(const float* __restrict__ x, __half* __restrict__ xh) {
    int i = blockIdx.x * blockDim.x + threadIdx.x; // one float4 per thread
    constexpr int TOT = N_NODESC * F_INC / 4;
    if (i >= TOT) return;
    float4 v = ((const float4*)x)[i];
    union { __half2 h[2]; uint2 u; } pk;
    pk.h[0] = __floats2half2_rn(v.x, v.y);
    pk.h[1] = __floats2half2_rn(v.z, v.w);
    ((uint2*)xh)[i] = pk.u;
}

// ---------------- K1: mean-gather x (fp16) -> agg (fp32, scaled) ----------------

__global__ __launch_bounds__(256) void gather1_kernel(
    const __half* __restrict__ xh, const int* __restrict__ row_ptr,
    const int* __restrict__ csr_src, const float* __restrict__ inv_deg,
    float* __restrict__ agg) {
    int gt = blockIdx.x * blockDim.x + threadIdx.x;
    int n = gt >> 2, l = gt & 3;
    if (n >= N_NODESC) return;

    float a[F_INC];
#pragma unroll
    for (int k = 0; k < F_INC; k++) a[k] = 0.0f;

    int e0 = row_ptr[n], e1 = row_ptr[n + 1];
    int e = e0 + l;
    for (; e + 4 < e1; e += 8) {
        int s0 = csr_src[e];
        int s1 = csr_src[e + 4];
        const uint4* r0 = (const uint4*)(xh + (size_t)s0 * F_INC);
        const uint4* r1 = (const uint4*)(xh + (size_t)s1 * F_INC);
        uint4 u0 = r0[0], u1 = r0[1];
        uint4 w0 = r1[0], w1 = r1[1];
        const __half2* p;
        p = (const __half2*)&u0;
#pragma unroll
        for (int q = 0; q < 4; q++) { float2 f = __half22float2(p[q]); a[2*q] += f.x; a[2*q+1] += f.y; }
        p = (const __half2*)&u1;
#pragma unroll
        for (int q = 0; q < 4; q++) { float2 f = __half22float2(p[q]); a[8+2*q] += f.x; a[8+2*q+1] += f.y; }
        p = (const __half2*)&w0;
#pragma unroll
        for (int q = 0; q < 4; q++) { float2 f = __half22float2(p[q]); a[2*q] += f.x; a[2*q+1] += f.y; }
        p = (const __half2*)&w1;
#pragma unroll
        for (int q = 0; q < 4; q++) { float2 f = __half22float2(p[q]); a[8+2*q] += f.x; a[8+2*q+1] += f.y; }
    }
    if (e < e1) {
        int s0 = csr_src[e];
        const uint4* r0 = (const uint4*)(xh + (size_t)s0 * F_INC);
        uint4 u0 = r0[0], u1 = r0[1];
        const __half2* p = (const __half2*)&u0;
#pragma unroll
        for (int q = 0; q < 4; q++) { float2 f = __half22float2(p[q]); a[2*q] += f.x; a[2*q+1] += f.y; }
        p = (const __half2*)&u1;
#pragma unroll
        for (int q = 0; q < 4; q++) { float2 f = __half22float2(p[q]); a[8+2*q] += f.x; a[8+2*q+1] += f.y; }
    }

#pragma unroll
    for (int off = 1; off <= 2; off <<= 1) {
#pragma unroll
        for (int k = 0; k < F_INC; k++) a[k] += __shfl_xor(a[k], off);
    }

    float idg = inv_deg[n];
    float4 w;
    w.x = a[l*4+0] * idg; w.y = a[l*4+1] * idg;
    w.z = a[l*4+2] * idg; w.w = a[l*4+3] * idg;
    ((float4*)(agg + (size_t)n * F_INC))[l] = w;
}

// ------- K2: dense fused: h=relu(agg@W1l+b1+x@W1r); g=h@W2l (fp16); r=h@W2r+b2 -------

__global__ __launch_bounds__(256) void dense_kernel(
    const float* __restrict__ x, const float* __restrict__ agg,
    const float* __restrict__ W1l, const float* __restrict__ b1,
    const float* __restrict__ W1r, const float* __restrict__ W2l,
    const float* __restrict__ b2, const float* __restrict__ W2r,
    __half* __restrict__ g16, float* __restrict__ r) {
    __shared__ float sW1l[F_INC][F_HC];
    __shared__ float sW1r[F_INC][F_HC];
    __shared__ float sb1[F_HC];
    __shared__ float sW2l[F_HC][F_OUTC];
    __shared__ float sW2r[F_HC][F_OUTC];
    __shared__ float sb2[F_OUTC];
    for (int i = threadIdx.x; i < F_INC * F_HC; i += blockDim.x) {
        sW1l[i / F_HC][i % F_HC] = W1l[i];
        sW1r[i / F_HC][i % F_HC] = W1r[i];
    }
    for (int i = threadIdx.x; i < F_HC * F_OUTC; i += blockDim.x) {
        sW2l[i / F_OUTC][i % F_OUTC] = W2l[i];
        sW2r[i / F_OUTC][i % F_OUTC] = W2r[i];
    }
    if (threadIdx.x < F_HC) sb1[threadIdx.x] = b1[threadIdx.x];
    if (threadIdx.x < F_OUTC) sb2[threadIdx.x] = b2[threadIdx.x];
    __syncthreads();

    int n = blockIdx.x * blockDim.x + threadIdx.x;
    if (n >= N_NODESC) return;

    float ag[F_INC], xr[F_INC];
    const float4* ap = (const float4*)(agg + (size_t)n * F_INC);
    const float4* xp = (const float4*)(x + (size_t)n * F_INC);
#pragma unroll
    for (int q = 0; q < F_INC / 4; q++) {
        float4 v = ap[q];
        ag[4*q] = v.x; ag[4*q+1] = v.y; ag[4*q+2] = v.z; ag[4*q+3] = v.w;
        float4 u = xp[q];
        xr[4*q] = u.x; xr[4*q+1] = u.y; xr[4*q+2] = u.z; xr[4*q+3] = u.w;
    }

    float h[F_HC];
#pragma unroll
    for (int f = 0; f < F_HC; f++) h[f] = sb1[f];
#pragma unroll
    for (int k = 0; k < F_INC; k++) {
        float a = ag[k], b = xr[k];
#pragma unroll
        for (int f = 0; f < F_HC; f++) h[f] += a * sW1l[k][f] + b * sW1r[k][f];
    }
#pragma unroll
    for (int f = 0; f < F_HC; f++) h[f] = fmaxf(h[f], 0.0f);

    float g[F_OUTC], rr[F_OUTC];
#pragma unroll
    for (int f = 0; f < F_OUTC; f++) { g[f] = 0.0f; rr[f] = sb2[f]; }
#pragma unroll
    for (int k = 0; k < F_HC; k++) {
        float hv = h[k];
#pragma unroll
        for (int f = 0; f < F_OUTC; f++) {
            g[f] += hv * sW2l[k][f];
            rr[f] += hv * sW2r[k][f];
        }
    }

    // g -> fp16, 64B-stride rows (32 halves, 24 used)
    __half* gp = g16 + (size_t)n * 32;
#pragma unroll
    for (int q = 0; q < F_OUTC / 8; q++) {
        union { __half2 h2[4]; uint4 u; } pk;
#pragma unroll
        for (int j = 0; j < 4; j++)
            pk.h2[j] = __floats2half2_rn(g[8*q + 2*j], g[8*q + 2*j + 1]);
        ((uint4*)gp)[q] = pk.u;
    }
    float4* rp = (float4*)(r + (size_t)n * F_OUTC);
#pragma unroll
    for (int q = 0; q < F_OUTC / 4; q++) {
        float4 v;
        v.x = rr[4*q]; v.y = rr[4*q+1]; v.z = rr[4*q+2]; v.w = rr[4*q+3];
        rp[q] = v;
    }
}

// ------- K3: mean-gather g (fp16) + r -> log_softmax -> out -------

__global__ __launch_bounds__(256) void gather2_kernel(
    const __half* __restrict__ g16, const int* __restrict__ row_ptr,
    const int* __restrict__ csr_src, const float* __restrict__ inv_deg,
    const float* __restrict__ r, float* __restrict__ out) {
    int gt = blockIdx.x * blockDim.x + threadIdx.x;
    int n = gt >> 2, l = gt & 3;
    if (n >= N_NODESC) return;

    float a[F_OUTC];
#pragma unroll
    for (int k = 0; k < F_OUTC; k++) a[k] = 0.0f;

    int e0 = row_ptr[n], e1 = row_ptr[n + 1];
    int e = e0 + l;
    for (; e + 4 < e1; e += 8) {
        int s0 = csr_src[e];
        int s1 = csr_src[e + 4];
        const uint4* r0 = (const uint4*)(g16 + (size_t)s0 * 32);
        const uint4* r1 = (const uint4*)(g16 + (size_t)s1 * 32);
        uint4 u0 = r0[0], u1 = r0[1], u2 = r0[2];
        uint4 w0 = r1[0], w1 = r1[1], w2 = r1[2];
        const __half2* p;
        p = (const __half2*)&u0;
#pragma unroll
        for (int q = 0; q < 4; q++) { float2 f = __half22float2(p[q]); a[2*q] += f.x; a[2*q+1] += f.y; }
        p = (const __half2*)&u1;
#pragma unroll
        for (int q = 0; q < 4; q++) { float2 f = __half22float2(p[q]); a[8+2*q] += f.x; a[8+2*q+1] += f.y; }
        p = (const __half2*)&u2;
#pragma unroll
        for (int q = 0; q < 4; q++) { float2 f = __half22float2(p[q]); a[16+2*q] += f.x; a[16+2*q+1] += f.y; }
        p = (const __half2*)&w0;
#pragma unroll
        for (int q = 0; q < 4; q++) { float2 f = __half22float2(p[q]); a[2*q] += f.x; a[2*q+1] += f.y; }
        p = (const __half2*)&w1;
#pragma unroll
        for (int q = 0; q < 4; q++) { float2 f = __half22float2(p[q]); a[8+2*q] += f.x; a[8+2*q+1] += f.y; }
        p = (const __half2*)&w2;
#pragma unroll
        for (int q = 0; q < 4; q++) { float2 f = __half22float2(p[q]); a[16+2*q] += f.x; a[16+2*q+1] += f.y; }
    }
    if (e < e1) {
        int s0 = csr_src[e];
        const uint4* r0 = (const uint4*)(g16 + (size_t)s0 * 32);
        uint4 u0 = r0[0], u1 = r0[1], u2 = r0[2];
        const __half2* p = (const __half2*)&u0;
#pragma unroll
        for (int q = 0; q < 4; q++) { float2 f = __half22float2(p[q]); a[2*q] += f.x; a[2*q+1] += f.y; }
        p = (const __half2*)&u1;
#pragma unroll
        for (int q = 0; q < 4; q++) { float2 f = __half22float2(p[q]); a[8+2*q] += f.x; a[8+2*q+1] += f.y; }
        p = (const __half2*)&u2;
#pragma unroll
        for (int q = 0; q < 4; q++) { float2 f = __half22float2(p[q]); a[16+2*q] += f.x; a[16+2*q+1] += f.y; }
    }

#pragma unroll
    for (int off = 1; off <= 2; off <<= 1) {
#pragma unroll
        for (int k = 0; k < F_OUTC; k++) a[k] += __shfl_xor(a[k], off);
    }

    float idg = inv_deg[n];
    const float* rb = r + (size_t)n * F_OUTC + l * 6;
    float o[6];
#pragma unroll
    for (int j = 0; j < 6; j++) o[j] = a[l * 6 + j] * idg + rb[j];

    float m = o[0];
#pragma unroll
    for (int j = 1; j < 6; j++) m = fmaxf(m, o[j]);
    m = fmaxf(m, __shfl_xor(m, 1));
    m = fmaxf(m, __shfl_xor(m, 2));
    float s = 0.0f;
#pragma unroll
    for (int j = 0; j < 6; j++) s += __expf(o[j] - m);
    s += __shfl_xor(s, 1);
    s += __shfl_xor(s, 2);
    float lse = m + __logf(s);

    float* ob = out + (size_t)n * F_OUTC + l * 6;
#pragma unroll
    for (int j = 0; j < 6; j++) ob[j] = o[j] - lse;
}

// ---------------- launch ----------------

extern "C" void kernel_launch(void* const* d_in, const int* in_sizes, int n_in,
                              void* d_out, int out_size, void* d_ws, size_t ws_size,
                              hipStream_t stream) {
    const float* x   = (const float*)d_in[0];
    const int* eidx  = (const int*)d_in[1];
    const float* W1l = (const float*)d_in[2];
    const float* b1  = (const float*)d_in[3];
    const float* W1r = (const float*)d_in[4];
    const float* W2l = (const float*)d_in[5];
    const float* b2  = (const float*)d_in[6];
    const float* W2r = (const float*)d_in[7];
    float* out = (float*)d_out;

    const int* src = eidx;
    const int* tgt = eidx + N_EDGESC;

    char* ws = (char*)d_ws;
    size_t off = 0;
    auto alloc = [&](size_t bytes) {
        size_t o = off;
        off = (off + bytes + 255) & ~(size_t)255;
        return o;
    };
    int*    deg      = (int*)(ws + alloc((size_t)N_NODESC * 4)); // 800000B, 256-aligned size
    int*    bin_fill = (int*)(ws + alloc((size_t)NBIN * 4));     // adjacent to deg
    float*  inv_deg  = (float*)(ws + alloc((size_t)N_NODESC * 4));
    int*    row_ptr  = (int*)(ws + alloc((size_t)(N_NODESC + 1) * 4));
    int*    bsum     = (int*)(ws + alloc((size_t)NBLK * 4));
    int*    csr_src  = (int*)(ws + alloc((size_t)N_EDGESC * 4));
    __half* xh       = (__half*)(ws + alloc((size_t)N_NODESC * F_INC * 2));
    float*  agg      = (float*)(ws + alloc((size_t)N_NODESC * F_INC * 4)); // 12.8MB
    __half* g16      = (__half*)(ws + alloc((size_t)N_NODESC * 32 * 2));   // 12.8MB, adjacent
    float*  r        = (float*)(ws + alloc((size_t)N_NODESC * F_OUTC * 4));
    // pair_buf (25.6MB) overlays agg+g16: dead until gather1/dense run, and
    // both alloc sizes are 256-multiples so the regions are contiguous.
    int*    pair_buf = (int*)agg;
    (void)ws_size;

    // zero deg + bin_fill (contiguous: 800000 + padded 50176 bytes)
    hipMemsetAsync(deg, 0, (size_t)N_NODESC * 4 + (((size_t)NBIN * 4 + 255) & ~(size_t)255), stream);

    const int TB = 256;
    const int edgeBlocks = 2560; // multiple of 8 (deg bucketing requires it)
    deg_kernel<<<edgeBlocks, TB, 0, stream>>>(tgt, deg);
    cast_x_kernel<<<(N_NODESC * F_INC / 4 + TB - 1) / TB, TB, 0, stream>>>(x, xh);
    scan1_kernel<<<NBLK, SCAN_BLOCK, 0, stream>>>(deg, inv_deg, row_ptr, bsum);
    scan2_kernel<<<1, 256, 0, stream>>>(bsum);
    scan3_kernel<<<NBLK, SCAN_BLOCK, 0, stream>>>(row_ptr, bsum);
    bin_kernel<<<edgeBlocks, TB, 0, stream>>>(src, tgt, row_ptr, bin_fill, pair_buf);
    unbin_kernel<<<NGRP, TB, 0, stream>>>(row_ptr, pair_buf, csr_src);

    const int lane4Blocks = ((N_NODESC * 4) + TB - 1) / TB; // 3125
    gather1_kernel<<<lane4Blocks, TB, 0, stream>>>(xh, row_ptr, csr_src, inv_deg, agg);
    dense_kernel<<<(N_NODESC + TB - 1) / TB, TB, 0, stream>>>(
        x, agg, W1l, b1, W1r, W2l, b2, W2r, g16, r);
    gather2_kernel<<<lane4Blocks, TB, 0, stream>>>(g16, row_ptr, csr_src, inv_deg, r, out);
}

// Round 14
// 476.011 us; speedup vs baseline: 2.0135x; 2.0106x over previous
//
#include <hip/hip_runtime.h>
#include <hip/hip_fp16.h>
#include <cstdint>

// GraphSAGE 2-layer, N=200000, E=6400000, F 16->40->24, fp32 in/out.
// Gathers: CSR + algebraic push-through (g=h@W2l fp16 64B rows, r=h@W2r+b2;
// layer2 = log_softmax(mean(g[src]) + r); h never materialized).
// CSR build is a 2-PASS LDS-STAGED COUNTING SORT (r8/r12/r13 all showed
// ~16x write-back amplification for any scatter whose per-line stores come
// from different CUs over time; only block-local line assembly fixes it):
//  bin2:  per-block tile of 4096 edges -> LDS hist over 196 coarse buckets
//         (1024 nodes) -> scan -> one global cursor atomic per bucket ->
//         bucket-sorted LDS stash -> coalesced run flush to b*CAP regions.
//  bscan: scan 196 bucket counts -> bucket edge bases; row_ptr[N]=E.
//  unbin2: block per bucket: LDS per-node hist -> scan -> row_ptr+inv_deg
//         (replaces deg/scan1-3) -> scatter into the bucket's 130KB csr
//         window (one block, tight time window -> write-once lines).
// pair_buf (196*34000*4B=26.7MB) overlays agg+g16+r (dead until gather1).

#define N_NODESC 200000
#define N_EDGESC 6400000
#define F_INC 16
#define F_HC 40
#define F_OUTC 24

constexpr int BSHIFT = 10;                 // 1024 nodes per coarse bucket
constexpr int NB2 = (N_NODESC + 1023) / 1024; // 196 buckets (last has 672)
constexpr int CAPB = 34000;                // bucket capacity (mean 32653 + 7.5 sigma)
constexpr int TILE = 4096;                 // edges per bin2 block
constexpr int NTILE = (N_EDGESC + TILE - 1) / TILE; // 1563

// ---------------- CSR build: pass 1 (tile sort into coarse buckets) ----------------

__global__ __launch_bounds__(256) void bin2_kernel(
    const int* __restrict__ src, const int* __restrict__ tgt,
    int* __restrict__ gcur, int* __restrict__ pair_buf) {
    __shared__ int hist[NB2];
    __shared__ int lbase[NB2];
    __shared__ int gbase[NB2];
    __shared__ int scan_tmp[256];
    __shared__ int stash[TILE];
    __shared__ int sadd[TILE];
    __shared__ int stot;
    int tid = threadIdx.x;
    for (int i = tid; i < NB2; i += 256) hist[i] = 0;
    __syncthreads();

    // Phase A: read 16 edges (4 x int4, coalesced), LDS-hist rank
    int gi0 = blockIdx.x * (TILE / 4);
    int entries[16];
    int bbrr[16]; // (bucket<<16)|rank, or -1 invalid
#pragma unroll
    for (int j = 0; j < 4; j++) {
        int gi = gi0 + tid + 256 * j;
        if (gi < N_EDGESC / 4) {
            int4 t = ((const int4*)tgt)[gi];
            int4 s = ((const int4*)src)[gi];
            int tt[4] = {t.x, t.y, t.z, t.w};
            int ss[4] = {s.x, s.y, s.z, s.w};
#pragma unroll
            for (int q = 0; q < 4; q++) {
                int b = tt[q] >> BSHIFT;
                int r = atomicAdd(&hist[b], 1); // rank within tile-bucket (<4096)
                entries[j * 4 + q] = (ss[q] << BSHIFT) | (tt[q] & ((1 << BSHIFT) - 1));
                bbrr[j * 4 + q] = (b << 16) | r;
            }
        } else {
#pragma unroll
            for (int q = 0; q < 4; q++) bbrr[j * 4 + q] = -1;
        }
    }
    __syncthreads();

    // Phase B: exclusive scan hist -> lbase; reserve global chunk per bucket
    int v = (tid < NB2) ? hist[tid] : 0;
    scan_tmp[tid] = v;
    __syncthreads();
    for (int off = 1; off < 256; off <<= 1) {
        int u = (tid >= off) ? scan_tmp[tid - off] : 0;
        __syncthreads();
        scan_tmp[tid] += u;
        __syncthreads();
    }
    if (tid < NB2) {
        lbase[tid] = scan_tmp[tid] - v;
        gbase[tid] = (v > 0) ? atomicAdd(&gcur[tid], v) : 0;
    }
    if (tid == 255) stot = scan_tmp[255];
    __syncthreads();

    // Phase C: place entries bucket-sorted into stash (+ global addr)
#pragma unroll
    for (int j = 0; j < 16; j++) {
        int br = bbrr[j];
        if (br >= 0) {
            int b = br >> 16, r = br & 0xFFFF;
            int idx = lbase[b] + r;
            stash[idx] = entries[j];
            sadd[idx] = b * CAPB + gbase[b] + r;
        }
    }
    __syncthreads();

    // Phase D: coalesced flush (stash is bucket-sorted -> run-contiguous addrs)
    int tot = stot;
    for (int k = tid; k < tot; k += 256) {
        pair_buf[sadd[k]] = stash[k];
    }
}

// ---------------- pass 1.5: scan bucket counts ----------------

__global__ void bscan_kernel(const int* __restrict__ gcur, int* __restrict__ bbase,
                             int* __restrict__ row_ptr) {
    __shared__ int tmp[256];
    int t = threadIdx.x;
    int v = (t < NB2) ? gcur[t] : 0;
    tmp[t] = v;
    __syncthreads();
    for (int off = 1; off < 256; off <<= 1) {
        int u = (t >= off) ? tmp[t - off] : 0;
        __syncthreads();
        tmp[t] += u;
        __syncthreads();
    }
    if (t < NB2) bbase[t] = tmp[t] - v; // exclusive
    if (t == 0) row_ptr[N_NODESC] = N_EDGESC;
}

// ---------------- pass 2: per-bucket fine sort + row_ptr + inv_deg ----------------

__global__ __launch_bounds__(256) void unbin2_kernel(
    const int* __restrict__ gcur, const int* __restrict__ bbase,
    const int* __restrict__ pair_buf, int* __restrict__ row_ptr,
    float* __restrict__ inv_deg, int* __restrict__ csr_src) {
    __shared__ int hist[1024];
    __shared__ int lofs[1024];
    __shared__ int fill[1024];
    __shared__ int part[256];
    int tid = threadIdx.x;
    int b = blockIdx.x;
    int cnt = gcur[b];
    int ebase = bbase[b];
    const int* pb = pair_buf + (size_t)b * CAPB;
    int n0 = b << BSHIFT;
    int ncount = min(1024, N_NODESC - n0);
#pragma unroll
    for (int j = 0; j < 4; j++) { hist[tid + 256 * j] = 0; fill[tid + 256 * j] = 0; }
    __syncthreads();
    // per-node histogram
    for (int k = tid; k < cnt; k += 256) atomicAdd(&hist[pb[k] & 1023], 1);
    __syncthreads();
    // exclusive scan of 1024 (4 per thread + block scan of partials)
    int h0 = hist[tid * 4], h1 = hist[tid * 4 + 1], h2 = hist[tid * 4 + 2], h3 = hist[tid * 4 + 3];
    int psum = h0 + h1 + h2 + h3;
    part[tid] = psum;
    __syncthreads();
    for (int off = 1; off < 256; off <<= 1) {
        int u = (tid >= off) ? part[tid - off] : 0;
        __syncthreads();
        part[tid] += u;
        __syncthreads();
    }
    int ex = part[tid] - psum;
    lofs[tid * 4] = ex;
    lofs[tid * 4 + 1] = ex + h0;
    lofs[tid * 4 + 2] = ex + h0 + h1;
    lofs[tid * 4 + 3] = ex + h0 + h1 + h2;
    __syncthreads();
    // row_ptr + inv_deg for this bucket's nodes
#pragma unroll
    for (int j = 0; j < 4; j++) {
        int i = tid + 256 * j;
        if (i < ncount) {
            row_ptr[n0 + i] = ebase + lofs[i];
            int d = hist[i];
            inv_deg[n0 + i] = (d > 0) ? 1.0f / (float)d : 0.0f;
        }
    }
    __syncthreads();
    // scatter into the bucket's contiguous csr window (~130KB, one block)
    for (int k = tid; k < cnt; k += 256) {
        int v = pb[k];
        int nl = v & 1023;
        int rk = atomicAdd(&fill[nl], 1);
        csr_src[ebase + lofs[nl] + rk] = v >> BSHIFT;
    }
}

// ---------------- x -> fp16 cast ----------------

__global__ void cast_x_kernel(const float* __restrict__ x, __half* __restrict__ xh) {
    int i = blockIdx.x * blockDim.x + threadIdx.x; // one float4 per thread
    constexpr int TOT = N_NODESC * F_INC / 4;
    if (i >= TOT) return;
    float4 v = ((const float4*)x)[i];
    union { __half2 h[2]; uint2 u; } pk;
    pk.h[0] = __floats2half2_rn(v.x, v.y);
    pk.h[1] = __floats2half2_rn(v.z, v.w);
    ((uint2*)xh)[i] = pk.u;
}

// ---------------- K1: mean-gather x (fp16) -> agg (fp32, scaled) ----------------

__global__ __launch_bounds__(256) void gather1_kernel(
    const __half* __restrict__ xh, const int* __restrict__ row_ptr,
    const int* __restrict__ csr_src, const float* __restrict__ inv_deg,
    float* __restrict__ agg) {
    int gt = blockIdx.x * blockDim.x + threadIdx.x;
    int n = gt >> 2, l = gt & 3;
    if (n >= N_NODESC) return;

    float a[F_INC];
#pragma unroll
    for (int k = 0; k < F_INC; k++) a[k] = 0.0f;

    int e0 = row_ptr[n], e1 = row_ptr[n + 1];
    int e = e0 + l;
    for (; e + 4 < e1; e += 8) {
        int s0 = csr_src[e];
        int s1 = csr_src[e + 4];
        const uint4* r0 = (const uint4*)(xh + (size_t)s0 * F_INC);
        const uint4* r1 = (const uint4*)(xh + (size_t)s1 * F_INC);
        uint4 u0 = r0[0], u1 = r0[1];
        uint4 w0 = r1[0], w1 = r1[1];
        const __half2* p;
        p = (const __half2*)&u0;
#pragma unroll
        for (int q = 0; q < 4; q++) { float2 f = __half22float2(p[q]); a[2*q] += f.x; a[2*q+1] += f.y; }
        p = (const __half2*)&u1;
#pragma unroll
        for (int q = 0; q < 4; q++) { float2 f = __half22float2(p[q]); a[8+2*q] += f.x; a[8+2*q+1] += f.y; }
        p = (const __half2*)&w0;
#pragma unroll
        for (int q = 0; q < 4; q++) { float2 f = __half22float2(p[q]); a[2*q] += f.x; a[2*q+1] += f.y; }
        p = (const __half2*)&w1;
#pragma unroll
        for (int q = 0; q < 4; q++) { float2 f = __half22float2(p[q]); a[8+2*q] += f.x; a[8+2*q+1] += f.y; }
    }
    if (e < e1) {
        int s0 = csr_src[e];
        const uint4* r0 = (const uint4*)(xh + (size_t)s0 * F_INC);
        uint4 u0 = r0[0], u1 = r0[1];
        const __half2* p = (const __half2*)&u0;
#pragma unroll
        for (int q = 0; q < 4; q++) { float2 f = __half22float2(p[q]); a[2*q] += f.x; a[2*q+1] += f.y; }
        p = (const __half2*)&u1;
#pragma unroll
        for (int q = 0; q < 4; q++) { float2 f = __half22float2(p[q]); a[8+2*q] += f.x; a[8+2*q+1] += f.y; }
    }

#pragma unroll
    for (int off = 1; off <= 2; off <<= 1) {
#pragma unroll
        for (int k = 0; k < F_INC; k++) a[k] += __shfl_xor(a[k], off);
    }

    float idg = inv_deg[n];
    float4 w;
    w.x = a[l*4+0] * idg; w.y = a[l*4+1] * idg;
    w.z = a[l*4+2] * idg; w.w = a[l*4+3] * idg;
    ((float4*)(agg + (size_t)n * F_INC))[l] = w;
}

// ------- K2: dense fused: h=relu(agg@W1l+b1+x@W1r); g=h@W2l (fp16); r=h@W2r+b2 -------

__global__ __launch_bounds__(256) void dense_kernel(
    const float* __restrict__ x, const float* __restrict__ agg,
    const float* __restrict__ W1l, const float* __restrict__ b1,
    const float* __restrict__ W1r, const float* __restrict__ W2l,
    const float* __restrict__ b2, const float* __restrict__ W2r,
    __half* __restrict__ g16, float* __restrict__ r) {
    __shared__ float sW1l[F_INC][F_HC];
    __shared__ float sW1r[F_INC][F_HC];
    __shared__ float sb1[F_HC];
    __shared__ float sW2l[F_HC][F_OUTC];
    __shared__ float sW2r[F_HC][F_OUTC];
    __shared__ float sb2[F_OUTC];
    for (int i = threadIdx.x; i < F_INC * F_HC; i += blockDim.x) {
        sW1l[i / F_HC][i % F_HC] = W1l[i];
        sW1r[i / F_HC][i % F_HC] = W1r[i];
    }
    for (int i = threadIdx.x; i < F_HC * F_OUTC; i += blockDim.x) {
        sW2l[i / F_OUTC][i % F_OUTC] = W2l[i];
        sW2r[i / F_OUTC][i % F_OUTC] = W2r[i];
    }
    if (threadIdx.x < F_HC) sb1[threadIdx.x] = b1[threadIdx.x];
    if (threadIdx.x < F_OUTC) sb2[threadIdx.x] = b2[threadIdx.x];
    __syncthreads();

    int n = blockIdx.x * blockDim.x + threadIdx.x;
    if (n >= N_NODESC) return;

    float ag[F_INC], xr[F_INC];
    const float4* ap = (const float4*)(agg + (size_t)n * F_INC);
    const float4* xp = (const float4*)(x + (size_t)n * F_INC);
#pragma unroll
    for (int q = 0; q < F_INC / 4; q++) {
        float4 v = ap[q];
        ag[4*q] = v.x; ag[4*q+1] = v.y; ag[4*q+2] = v.z; ag[4*q+3] = v.w;
        float4 u = xp[q];
        xr[4*q] = u.x; xr[4*q+1] = u.y; xr[4*q+2] = u.z; xr[4*q+3] = u.w;
    }

    float h[F_HC];
#pragma unroll
    for (int f = 0; f < F_HC; f++) h[f] = sb1[f];
#pragma unroll
    for (int k = 0; k < F_INC; k++) {
        float a = ag[k], b = xr[k];
#pragma unroll
        for (int f = 0; f < F_HC; f++) h[f] += a * sW1l[k][f] + b * sW1r[k][f];
    }
#pragma unroll
    for (int f = 0; f < F_HC; f++) h[f] = fmaxf(h[f], 0.0f);

    float g[F_OUTC], rr[F_OUTC];
#pragma unroll
    for (int f = 0; f < F_OUTC; f++) { g[f] = 0.0f; rr[f] = sb2[f]; }
#pragma unroll
    for (int k = 0; k < F_HC; k++) {
        float hv = h[k];
#pragma unroll
        for (int f = 0; f < F_OUTC; f++) {
            g[f] += hv * sW2l[k][f];
            rr[f] += hv * sW2r[k][f];
        }
    }

    // g -> fp16, 64B-stride rows (32 halves, 24 used)
    __half* gp = g16 + (size_t)n * 32;
#pragma unroll
    for (int q = 0; q < F_OUTC / 8; q++) {
        union { __half2 h2[4]; uint4 u; } pk;
#pragma unroll
        for (int j = 0; j < 4; j++)
            pk.h2[j] = __floats2half2_rn(g[8*q + 2*j], g[8*q + 2*j + 1]);
        ((uint4*)gp)[q] = pk.u;
    }
    float4* rp = (float4*)(r + (size_t)n * F_OUTC);
#pragma unroll
    for (int q = 0; q < F_OUTC / 4; q++) {
        float4 v;
        v.x = rr[4*q]; v.y = rr[4*q+1]; v.z = rr[4*q+2]; v.w = rr[4*q+3];
        rp[q] = v;
    }
}

// ------- K3: mean-gather g (fp16) + r -> log_softmax -> out -------

__global__ __launch_bounds__(256) void gather2_kernel(
    const __half* __restrict__ g16, const int* __restrict__ row_ptr,
    const int* __restrict__ csr_src, const float* __restrict__ inv_deg,
    const float* __restrict__ r, float* __restrict__ out) {
    int gt = blockIdx.x * blockDim.x + threadIdx.x;
    int n = gt >> 2, l = gt & 3;
    if (n >= N_NODESC) return;

    float a[F_OUTC];
#pragma unroll
    for (int k = 0; k < F_OUTC; k++) a[k] = 0.0f;

    int e0 = row_ptr[n], e1 = row_ptr[n + 1];
    int e = e0 + l;
    for (; e + 4 < e1; e += 8) {
        int s0 = csr_src[e];
        int s1 = csr_src[e + 4];
        const uint4* r0 = (const uint4*)(g16 + (size_t)s0 * 32);
        const uint4* r1 = (const uint4*)(g16 + (size_t)s1 * 32);
        uint4 u0 = r0[0], u1 = r0[1], u2 = r0[2];
        uint4 w0 = r1[0], w1 = r1[1], w2 = r1[2];
        const __half2* p;
        p = (const __half2*)&u0;
#pragma unroll
        for (int q = 0; q < 4; q++) { float2 f = __half22float2(p[q]); a[2*q] += f.x; a[2*q+1] += f.y; }
        p = (const __half2*)&u1;
#pragma unroll
        for (int q = 0; q < 4; q++) { float2 f = __half22float2(p[q]); a[8+2*q] += f.x; a[8+2*q+1] += f.y; }
        p = (const __half2*)&u2;
#pragma unroll
        for (int q = 0; q < 4; q++) { float2 f = __half22float2(p[q]); a[16+2*q] += f.x; a[16+2*q+1] += f.y; }
        p = (const __half2*)&w0;
#pragma unroll
        for (int q = 0; q < 4; q++) { float2 f = __half22float2(p[q]); a[2*q] += f.x; a[2*q+1] += f.y; }
        p = (const __half2*)&w1;
#pragma unroll
        for (int q = 0; q < 4; q++) { float2 f = __half22float2(p[q]); a[8+2*q] += f.x; a[8+2*q+1] += f.y; }
        p = (const __half2*)&w2;
#pragma unroll
        for (int q = 0; q < 4; q++) { float2 f = __half22float2(p[q]); a[16+2*q] += f.x; a[16+2*q+1] += f.y; }
    }
    if (e < e1) {
        int s0 = csr_src[e];
        const uint4* r0 = (const uint4*)(g16 + (size_t)s0 * 32);
        uint4 u0 = r0[0], u1 = r0[1], u2 = r0[2];
        const __half2* p = (const __half2*)&u0;
#pragma unroll
        for (int q = 0; q < 4; q++) { float2 f = __half22float2(p[q]); a[2*q] += f.x; a[2*q+1] += f.y; }
        p = (const __half2*)&u1;
#pragma unroll
        for (int q = 0; q < 4; q++) { float2 f = __half22float2(p[q]); a[8+2*q] += f.x; a[8+2*q+1] += f.y; }
        p = (const __half2*)&u2;
#pragma unroll
        for (int q = 0; q < 4; q++) { float2 f = __half22float2(p[q]); a[16+2*q] += f.x; a[16+2*q+1] += f.y; }
    }

#pragma unroll
    for (int off = 1; off <= 2; off <<= 1) {
#pragma unroll
        for (int k = 0; k < F_OUTC; k++) a[k] += __shfl_xor(a[k], off);
    }

    float idg = inv_deg[n];
    const float* rb = r + (size_t)n * F_OUTC + l * 6;
    float o[6];
#pragma unroll
    for (int j = 0; j < 6; j++) o[j] = a[l * 6 + j] * idg + rb[j];

    float m = o[0];
#pragma unroll
    for (int j = 1; j < 6; j++) m = fmaxf(m, o[j]);
    m = fmaxf(m, __shfl_xor(m, 1));
    m = fmaxf(m, __shfl_xor(m, 2));
    float s = 0.0f;
#pragma unroll
    for (int j = 0; j < 6; j++) s += __expf(o[j] - m);
    s += __shfl_xor(s, 1);
    s += __shfl_xor(s, 2);
    float lse = m + __logf(s);

    float* ob = out + (size_t)n * F_OUTC + l * 6;
#pragma unroll
    for (int j = 0; j < 6; j++) ob[j] = o[j] - lse;
}

// ---------------- launch ----------------

extern "C" void kernel_launch(void* const* d_in, const int* in_sizes, int n_in,
                              void* d_out, int out_size, void* d_ws, size_t ws_size,
                              hipStream_t stream) {
    const float* x   = (const float*)d_in[0];
    const int* eidx  = (const int*)d_in[1];
    const float* W1l = (const float*)d_in[2];
    const float* b1  = (const float*)d_in[3];
    const float* W1r = (const float*)d_in[4];
    const float* W2l = (const float*)d_in[5];
    const float* b2  = (const float*)d_in[6];
    const float* W2r = (const float*)d_in[7];
    float* out = (float*)d_out;

    const int* src = eidx;
    const int* tgt = eidx + N_EDGESC;

    char* ws = (char*)d_ws;
    size_t off = 0;
    auto alloc = [&](size_t bytes) {
        size_t o = off;
        off = (off + bytes + 255) & ~(size_t)255;
        return o;
    };
    int*    gcur     = (int*)(ws + alloc((size_t)NB2 * 4));
    int*    bbase    = (int*)(ws + alloc((size_t)NB2 * 4));
    float*  inv_deg  = (float*)(ws + alloc((size_t)N_NODESC * 4));
    int*    row_ptr  = (int*)(ws + alloc((size_t)(N_NODESC + 1) * 4));
    int*    csr_src  = (int*)(ws + alloc((size_t)N_EDGESC * 4));
    __half* xh       = (__half*)(ws + alloc((size_t)N_NODESC * F_INC * 2));
    float*  agg      = (float*)(ws + alloc((size_t)N_NODESC * F_INC * 4)); // 12.8MB
    __half* g16      = (__half*)(ws + alloc((size_t)N_NODESC * 32 * 2));   // 12.8MB
    float*  r        = (float*)(ws + alloc((size_t)N_NODESC * F_OUTC * 4)); // 19.2MB
    // pair_buf (196*34000*4B = 26.66MB) overlays agg+g16+r (44.8MB):
    // dead before gather1/dense run; all alloc sizes 256-multiples.
    int*    pair_buf = (int*)agg;
    (void)ws_size;

    hipMemsetAsync(gcur, 0, (size_t)NB2 * 4, stream);

    const int TB = 256;
    cast_x_kernel<<<(N_NODESC * F_INC / 4 + TB - 1) / TB, TB, 0, stream>>>(x, xh);
    bin2_kernel<<<NTILE, TB, 0, stream>>>(src, tgt, gcur, pair_buf);
    bscan_kernel<<<1, TB, 0, stream>>>(gcur, bbase, row_ptr);
    unbin2_kernel<<<NB2, TB, 0, stream>>>(gcur, bbase, pair_buf, row_ptr, inv_deg, csr_src);

    const int lane4Blocks = ((N_NODESC * 4) + TB - 1) / TB; // 3125
    gather1_kernel<<<lane4Blocks, TB, 0, stream>>>(xh, row_ptr, csr_src, inv_deg, agg);
    dense_kernel<<<(N_NODESC + TB - 1) / TB, TB, 0, stream>>>(
        x, agg, W1l, b1, W1r, W2l, b2, W2r, g16, r);
    gather2_kernel<<<lane4Blocks, TB, 0, stream>>>(g16, row_ptr, csr_src, inv_deg, r, out);
}